// Round 11
// baseline (154.467 us; speedup 1.0000x reference)
//
#include <hip/hip_runtime.h>
#include <math.h>

#define NPTS 256
#define FDIM 512
#define H1   300
#define KP   320    // padded K (H1 -> 320)
#define H2   100
#define NP   112    // padded N (H2 -> 112)

typedef _Float16 half8  __attribute__((ext_vector_type(8)));
typedef _Float16 half2v __attribute__((ext_vector_type(2)));
typedef float    floatx4 __attribute__((ext_vector_type(4)));

// ---- workspace layout (byte offsets) ----
#define OFF_AP    0          // ap f16 [4 j][2 b][256 n][320 k]   : 1,310,720 B
#define OFF_KW2F  1310720    // kw2 f16 B-frag order [10][7][64][8]: 71,680 B
#define OFF_PNW   1382400    // pointnet weights f16 frag order   :   229,376 B
#define OFF_KW1F  1611776    // kw1 f16 frag order [2][16][20][512]: 655,360 B
#define OFF_R     2267136    // R fp32 [2][256][256]              :   524,288 B
#define OFF_WGT   2791424    // weight fp32 [2][256]              :     2,048 B

// ============ prep: kw2 -> B-frag order; pn + kw1 weights -> B-frag order ============
__global__ __launch_bounds__(256) void k_prep(
    const float* __restrict__ kw2, const float* __restrict__ kw1,
    const float* __restrict__ pw0, const float* __restrict__ pw1,
    const float* __restrict__ pw2, const float* __restrict__ pw3,
    const float* __restrict__ pw4,
    _Float16* __restrict__ kw2ff, _Float16* __restrict__ pnw,
    _Float16* __restrict__ kw1f)
{
    int idx = blockIdx.x * 256 + threadIdx.x;
    if (idx < 35840) {                       // kw2ff [kc10][nt7][64][8]
        int e = idx & 7, lane = (idx >> 3) & 63, r = idx >> 9;   // r 0..69
        int nt = r % 7, kc = r / 7;
        int g = nt * 16 + (lane & 15);
        int k = kc * 32 + ((lane >> 4) << 3) + e;
        kw2ff[idx] = (_Float16)((g < H2 && k < H1) ? kw2[g * H1 + k] : 0.f);
        return;
    }
    int i = idx - 35840;
    if (i < 114688) {                        // pointnet frags
        const float* src; int K, NT, off;
        if      (i < 32768) { src = pw0; K = 512; NT = 4;  off = 0; }
        else if (i < 36864) { src = pw1; K = 64;  NT = 4;  off = 32768; }
        else if (i < 40960) { src = pw2; K = 64;  NT = 4;  off = 36864; }
        else if (i < 49152) { src = pw3; K = 64;  NT = 8;  off = 40960; }
        else                { src = pw4; K = 128; NT = 32; off = 49152; }
        int li = i - off;
        int e = li & 7, l = (li >> 3) & 63, r = li >> 9;
        int nt = r % NT, s = r / NT;
        int o = nt * 16 + (l & 15);
        int c = s * 32 + ((l >> 4) << 3) + e;
        pnw[i] = (_Float16)src[o * K + c];
        return;
    }
    i -= 114688;
    if (i < 327680) {                        // kw1 frags [half][s16][nt20][64][8]
        int e = i & 7, l = (i >> 3) & 63, r = i >> 9;     // r 0..639
        int nt = r % 20, s = (r / 20) & 15, half = r / 320;
        int h = nt * 16 + (l & 15);
        int c = s * 32 + ((l >> 4) << 3) + e;
        kw1f[i] = (_Float16)((h < H1) ? kw1[h * (2 * FDIM) + half * FDIM + c] : 0.f);
    }
}

// ============ merged mid kernel: blockIdx.y 0..7 -> apart GEMMs, 8..9 -> pointnet ========
#define XSTR 520
__global__ __launch_bounds__(256) void k_mid(
    const float* __restrict__ embA, const float* __restrict__ embB,
    const _Float16* __restrict__ kw1f, const float* __restrict__ kb1,
    _Float16* __restrict__ ap,
    const _Float16* __restrict__ pnw,
    const float* __restrict__ pb0, const float* __restrict__ pb1,
    const float* __restrict__ pb2, const float* __restrict__ pb3,
    const float* __restrict__ pb4, const float* __restrict__ headw,
    float* __restrict__ wgt)
{
    __shared__ __align__(16) _Float16 sX[16 * XSTR];
    __shared__ __align__(16) _Float16 sH[16][136];
    __shared__ float sVp[4][16];

    const int tid = threadIdx.x;
    const int wave = tid >> 6, lane = tid & 63;
    const int l15 = lane & 15, quad = lane >> 4;

    if (blockIdx.y < 8) {
        // ---------------- apart path ----------------
        const int ntile = blockIdx.x, jb = blockIdx.y;
        const int j = jb >> 1, b = jb & 1;
        const int n0 = ntile * 16;

        const float* emb = ((j < 2) ? embA : embB) + b * FDIM * NPTS;
        {
            const int n = tid & 15, fp = tid >> 4;
            const float* src = emb + n0 + n;
            _Float16* dst = &sX[n * XSTR];
            #pragma unroll
            for (int i = 0; i < 16; ++i) {
                int f = 2 * fp + 32 * i;
                float e0 = src[(size_t)f * NPTS];
                float e1 = src[(size_t)(f + 1) * NPTS];
                half2v hv; hv.x = (_Float16)e0; hv.y = (_Float16)e1;
                *reinterpret_cast<half2v*>(&dst[f]) = hv;
            }
        }

        const _Float16* wf = kw1f + (size_t)(j & 1) * 163840;
        floatx4 acc[5];
        #pragma unroll
        for (int q = 0; q < 5; ++q) acc[q] = (floatx4){0.f, 0.f, 0.f, 0.f};

        __syncthreads();

        const _Float16* arow = &sX[l15 * XSTR + quad * 8];
        #pragma unroll 4
        for (int s = 0; s < 16; ++s) {
            half8 af = *reinterpret_cast<const half8*>(&arow[s * 32]);
            const _Float16* wrow = wf + ((size_t)(s * 20 + wave * 5) * 64 + lane) * 8;
            #pragma unroll
            for (int q = 0; q < 5; ++q) {
                half8 bf = *reinterpret_cast<const half8*>(wrow + q * 512);
                acc[q] = __builtin_amdgcn_mfma_f32_16x16x32_f16(af, bf, acc[q], 0, 0, 0);
            }
        }

        const bool addb = (j < 2);
        _Float16* apb = ap + (size_t)jb * NPTS * KP;
        #pragma unroll
        for (int q = 0; q < 5; ++q) {
            int nt = wave * 5 + q;
            int h = nt * 16 + l15;
            float bv = (addb && h < H1) ? kb1[h] : 0.f;
            #pragma unroll
            for (int r = 0; r < 4; ++r) {
                int n = n0 + quad * 4 + r;
                apb[(size_t)n * KP + h] = (_Float16)(acc[q][r] + bv);
            }
        }
        return;
    }

    // ---------------- pointnet path ----------------
    const int n0 = blockIdx.x * 16, b = blockIdx.y - 8;

    {
        const int n = tid & 15, fp = tid >> 4;
        const float* src = embA + (size_t)b * FDIM * NPTS + n0 + n;
        _Float16* dst = &sX[n * XSTR];
        #pragma unroll
        for (int i = 0; i < 16; ++i) {
            int f = 2 * fp + 32 * i;
            float e0 = src[(size_t)f * NPTS];
            float e1 = src[(size_t)(f + 1) * NPTS];
            half2v hv; hv.x = (_Float16)e0; hv.y = (_Float16)e1;
            *reinterpret_cast<half2v*>(&dst[f]) = hv;
        }
    }
    __syncthreads();

    const _Float16* w0f = pnw;
    const _Float16* w1f = pnw + 32768;
    const _Float16* w2f = pnw + 36864;
    const _Float16* w3f = pnw + 40960;
    const _Float16* w4f = pnw + 49152;

    {
        const _Float16* arow = &sX[l15 * XSTR + quad * 8];
        floatx4 acc = (floatx4){0.f, 0.f, 0.f, 0.f};
        #pragma unroll 4
        for (int s = 0; s < 16; ++s) {
            half8 af = *reinterpret_cast<const half8*>(&arow[s * 32]);
            half8 bf = *reinterpret_cast<const half8*>(w0f + ((size_t)(s * 4 + wave) * 64 + lane) * 8);
            acc = __builtin_amdgcn_mfma_f32_16x16x32_f16(af, bf, acc, 0, 0, 0);
        }
        int o = wave * 16 + l15;
        float bv = pb0[o];
        #pragma unroll
        for (int r = 0; r < 4; ++r)
            sH[quad * 4 + r][o] = (_Float16)fmaxf(acc[r] + bv, 0.f);
    }
    __syncthreads();

    const _Float16* wfs[2] = {w1f, w2f};
    const float* pbs[2] = {pb1, pb2};
    #pragma unroll
    for (int layer = 0; layer < 2; ++layer) {
        half8 a0 = *reinterpret_cast<const half8*>(&sH[l15][quad * 8]);
        half8 a1 = *reinterpret_cast<const half8*>(&sH[l15][32 + quad * 8]);
        half8 b0 = *reinterpret_cast<const half8*>(wfs[layer] + ((size_t)(wave) * 64 + lane) * 8);
        half8 b1 = *reinterpret_cast<const half8*>(wfs[layer] + ((size_t)(4 + wave) * 64 + lane) * 8);
        floatx4 ac = __builtin_amdgcn_mfma_f32_16x16x32_f16(a0, b0, (floatx4){0.f,0.f,0.f,0.f}, 0, 0, 0);
        ac = __builtin_amdgcn_mfma_f32_16x16x32_f16(a1, b1, ac, 0, 0, 0);
        __syncthreads();
        int o = wave * 16 + l15;
        float bv = pbs[layer][o];
        #pragma unroll
        for (int r = 0; r < 4; ++r)
            sH[quad * 4 + r][o] = (_Float16)fmaxf(ac[r] + bv, 0.f);
        __syncthreads();
    }

    {
        half8 a0 = *reinterpret_cast<const half8*>(&sH[l15][quad * 8]);
        half8 a1 = *reinterpret_cast<const half8*>(&sH[l15][32 + quad * 8]);
        floatx4 ac[2];
        #pragma unroll
        for (int q = 0; q < 2; ++q) {
            int nt = 2 * wave + q;
            half8 b0 = *reinterpret_cast<const half8*>(w3f + ((size_t)nt * 64 + lane) * 8);
            half8 b1 = *reinterpret_cast<const half8*>(w3f + ((size_t)(8 + nt) * 64 + lane) * 8);
            ac[q] = __builtin_amdgcn_mfma_f32_16x16x32_f16(a0, b0, (floatx4){0.f,0.f,0.f,0.f}, 0, 0, 0);
            ac[q] = __builtin_amdgcn_mfma_f32_16x16x32_f16(a1, b1, ac[q], 0, 0, 0);
        }
        __syncthreads();
        #pragma unroll
        for (int q = 0; q < 2; ++q) {
            int o = (2 * wave + q) * 16 + l15;
            float bv = pb3[o];
            #pragma unroll
            for (int r = 0; r < 4; ++r)
                sH[quad * 4 + r][o] = (_Float16)fmaxf(ac[q][r] + bv, 0.f);
        }
        __syncthreads();
    }

    half8 a4[4];
    #pragma unroll
    for (int s = 0; s < 4; ++s)
        a4[s] = *reinterpret_cast<const half8*>(&sH[l15][s * 32 + quad * 8]);
    float ps0 = 0.f, ps1 = 0.f, ps2 = 0.f, ps3 = 0.f;
    #pragma unroll 2
    for (int q = 0; q < 8; ++q) {
        int nt = wave * 8 + q;
        floatx4 a = (floatx4){0.f, 0.f, 0.f, 0.f};
        #pragma unroll
        for (int s = 0; s < 4; ++s) {
            half8 bf = *reinterpret_cast<const half8*>(w4f + ((size_t)(s * 32 + nt) * 64 + lane) * 8);
            a = __builtin_amdgcn_mfma_f32_16x16x32_f16(a4[s], bf, a, 0, 0, 0);
        }
        int o = nt * 16 + l15;
        float hwv = headw[o], b4v = pb4[o];
        ps0 = fmaf(hwv, fmaxf(a[0] + b4v, 0.f), ps0);
        ps1 = fmaf(hwv, fmaxf(a[1] + b4v, 0.f), ps1);
        ps2 = fmaf(hwv, fmaxf(a[2] + b4v, 0.f), ps2);
        ps3 = fmaf(hwv, fmaxf(a[3] + b4v, 0.f), ps3);
    }
    #pragma unroll
    for (int m = 1; m < 16; m <<= 1) {
        ps0 += __shfl_xor(ps0, m, 64);
        ps1 += __shfl_xor(ps1, m, 64);
        ps2 += __shfl_xor(ps2, m, 64);
        ps3 += __shfl_xor(ps3, m, 64);
    }
    if (l15 == 0) {
        sVp[wave][quad * 4 + 0] = ps0;
        sVp[wave][quad * 4 + 1] = ps1;
        sVp[wave][quad * 4 + 2] = ps2;
        sVp[wave][quad * 4 + 3] = ps3;
    }
    __syncthreads();
    if (tid < 16) {
        float s = sVp[0][tid] + sVp[1][tid] + sVp[2][tid] + sVp[3][tid];
        wgt[(size_t)b * NPTS + n0 + tid] = s;
    }
}

// ============ Kernel B: pair tail — kw2 staged in LDS (two 35 KB halves) ============
// acc[2][7]/wave (R10 mapping); B-frags via deterministic conflict-free ds_read_b128
// instead of per-wave L2 streams. LDS 62 KB -> 2 blocks/CU.
#define SA_STR 328
#define SW_HALF 17920   // 5 kc-chunks x 7 nt x 64 lanes x 8 f16
__global__ __launch_bounds__(256, 2) void k_pair(
    const _Float16* __restrict__ ap, const _Float16* __restrict__ kw2ff,
    const float* __restrict__ kb2, const float* __restrict__ kw3,
    const float* __restrict__ kb3, float* __restrict__ R)
{
    const int mt = blockIdx.x, nt = blockIdx.y, b = blockIdx.z;
    const int m0 = mt * 16, n0 = nt * 4;
    __shared__ __align__(16) _Float16 sA[8 * SA_STR];        // a1/a2 rows (4 each), 5.1 KB
    __shared__ __align__(16) _Float16 sBT[2 * 10 * 64 * 8];  // b-frags, 20 KB
    __shared__ __align__(16) _Float16 sW[SW_HALF];           // kw2 half, 35 KB
    __shared__ float sV[128];
    const int tid = threadIdx.x;
    const int wave = tid >> 6, lane = tid & 63;
    const int l15 = lane & 15, quad = lane >> 4;

    // ---- stage a-rows [t2][4 n][320] ----
    for (int idx = tid; idx < 320; idx += 256) {
        int row = idx / 40, col = (idx - row * 40) * 8;
        int t = row >> 2, r = row & 3;
        half8 v = *reinterpret_cast<const half8*>(
            &ap[(size_t)((t * 2 + b) * NPTS + n0 + r) * KP + col]);
        *reinterpret_cast<half8*>(&sA[row * SA_STR + col]) = v;
    }
    // ---- stage b-rows in frag order: sBT[t][kc][lane][8] ; t0<-b2(j3), t1<-b1(j2) ----
    for (int idx = tid; idx < 1280; idx += 256) {
        int ln = idx & 63, kc = (idx >> 6) % 10, t = idx / 640;
        int j = t ? 2 : 3;
        half8 v = *reinterpret_cast<const half8*>(
            &ap[(size_t)((j * 2 + b) * NPTS + m0 + (ln & 15)) * KP + kc * 32 + ((ln >> 4) << 3)]);
        *reinterpret_cast<half8*>(&sBT[(size_t)idx * 8]) = v;
    }
    // ---- stage kw2 half 0 (kc 0..4) ----
    for (int idx = tid; idx < 2240; idx += 256)
        *reinterpret_cast<half8*>(&sW[idx * 8]) =
            *reinterpret_cast<const half8*>(&kw2ff[idx * 8]);

    const int tail = wave >> 1;
    const _Float16* sBTt = &sBT[(size_t)tail * 10 * 64 * 8 + (size_t)lane * 8];
    const _Float16* aRow0 = &sA[(size_t)(tail * 4 + (wave & 1) * 2) * SA_STR + quad * 8];
    const _Float16* sWl = sW + (size_t)lane * 8;

    floatx4 acc[2][7];
    #pragma unroll
    for (int i = 0; i < 2; ++i)
        #pragma unroll
        for (int jj = 0; jj < 7; ++jj)
            acc[i][jj] = (floatx4){0.f, 0.f, 0.f, 0.f};

    #pragma unroll
    for (int half = 0; half < 2; ++half) {
        __syncthreads();   // staging of this half complete
        for (int kcL = 0; kcL < 5; ++kcL) {
            const int kc = half * 5 + kcL;
            half8 bfrag = *reinterpret_cast<const half8*>(&sBTt[(size_t)kc * 64 * 8]);
            half8 af[2];
            #pragma unroll
            for (int i = 0; i < 2; ++i) {
                half8 av = *reinterpret_cast<const half8*>(&aRow0[i * SA_STR + kc * 32]);
                half8 s = av + bfrag;
                half8 rv;
                #pragma unroll
                for (int e = 0; e < 8; ++e)
                    rv[e] = s[e] > (_Float16)0 ? s[e] : (_Float16)0;
                af[i] = rv;
            }
            #pragma unroll
            for (int jj = 0; jj < 7; ++jj) {
                half8 bw = *reinterpret_cast<const half8*>(&sWl[(size_t)(kcL * 7 + jj) * 512]);
                acc[0][jj] = __builtin_amdgcn_mfma_f32_16x16x32_f16(af[0], bw, acc[0][jj], 0, 0, 0);
                acc[1][jj] = __builtin_amdgcn_mfma_f32_16x16x32_f16(af[1], bw, acc[1][jj], 0, 0, 0);
            }
        }
        if (half == 0) {
            __syncthreads();   // all waves done with half 0 before overwrite
            for (int idx = tid; idx < 2240; idx += 256)
                *reinterpret_cast<half8*>(&sW[idx * 8]) =
                    *reinterpret_cast<const half8*>(&kw2ff[SW_HALF + idx * 8]);
        }
    }

    // ---- epilogue: bias+relu layer2, dot kw3, reduce over g(l15), combine tails ----
    float kw3v[7], kb2v[7];
    #pragma unroll
    for (int jj = 0; jj < 7; ++jj) {
        int g = jj * 16 + l15;
        kw3v[jj] = (g < H2) ? kw3[g] : 0.f;
        kb2v[jj] = (g < H2) ? kb2[g] : 0.f;
    }
    #pragma unroll
    for (int i = 0; i < 2; ++i) {
        float rv0 = 0.f, rv1 = 0.f, rv2 = 0.f, rv3 = 0.f;
        #pragma unroll
        for (int jj = 0; jj < 7; ++jj) {
            float w3 = kw3v[jj], b2 = kb2v[jj];
            rv0 = fmaf(w3, fmaxf(acc[i][jj][0] + b2, 0.f), rv0);
            rv1 = fmaf(w3, fmaxf(acc[i][jj][1] + b2, 0.f), rv1);
            rv2 = fmaf(w3, fmaxf(acc[i][jj][2] + b2, 0.f), rv2);
            rv3 = fmaf(w3, fmaxf(acc[i][jj][3] + b2, 0.f), rv3);
        }
        #pragma unroll
        for (int m = 1; m < 16; m <<= 1) {
            rv0 += __shfl_xor(rv0, m, 64);
            rv1 += __shfl_xor(rv1, m, 64);
            rv2 += __shfl_xor(rv2, m, 64);
            rv3 += __shfl_xor(rv3, m, 64);
        }
        if (l15 == 0) {
            int base = (tail * 4 + (wave & 1) * 2 + i) * 16 + quad * 4;
            sV[base + 0] = rv0; sV[base + 1] = rv1;
            sV[base + 2] = rv2; sV[base + 3] = rv3;
        }
    }
    __syncthreads();
    if (tid < 64) {
        float s = 0.5f * (sV[tid] + sV[64 + tid]) + kb3[0];
        float sp = fmaxf(s, 0.f) + log1pf(expf(-fabsf(s)));
        int n_l = tid >> 4, m_l = tid & 15;
        R[(size_t)(b * NPTS + n0 + n_l) * NPTS + m0 + m_l] = sp;
    }
}

// ============ fused multilateration setup + solve + epilogue ============
__global__ __launch_bounds__(256) void k_solve(
    const float* __restrict__ R, const float* __restrict__ anchor_pts,
    const float* __restrict__ action_pts, const float* __restrict__ weight,
    float* __restrict__ out)
{
    const int a0 = blockIdx.x * 32, b = blockIdx.y;
    __shared__ float apx[256], apy[256], apz[256], sq[256];
    __shared__ float red[256];
    __shared__ float mb[12];
    const int t = threadIdx.x;
    const float px = anchor_pts[b * 768 + t];
    const float py = anchor_pts[b * 768 + 256 + t];
    const float pz = anchor_pts[b * 768 + 512 + t];
    apx[t] = px; apy[t] = py; apz[t] = pz;
    sq[t] = px * px + py * py + pz * pz;
    float sums[9];
    {
        float vals[9] = {px, py, pz, px*px, px*py, px*pz, py*py, py*pz, pz*pz};
        #pragma unroll
        for (int k = 0; k < 9; ++k) {
            red[t] = vals[k]; __syncthreads();
            for (int s = 128; s > 0; s >>= 1) {
                if (t < s) red[t] += red[t + s];
                __syncthreads();
            }
            sums[k] = red[0]; __syncthreads();
        }
    }
    if (t == 0) {
        const float inv = 1.f / 256.f;
        float mx = sums[0]*inv, my = sums[1]*inv, mz = sums[2]*inv;
        float a_ = sums[3]*inv - mx*mx;
        float b_ = sums[4]*inv - mx*my;
        float c_ = sums[5]*inv - mx*mz;
        float d_ = sums[6]*inv - my*my;
        float e_ = sums[7]*inv - my*mz;
        float f_ = sums[8]*inv - mz*mz;
        float c00 = d_*f_ - e_*e_;
        float c01 = c_*e_ - b_*f_;
        float c02 = b_*e_ - c_*d_;
        float det = a_*c00 + b_*c01 + c_*c02;
        float id = 1.f / det;
        mb[0] = mx; mb[1] = my; mb[2] = mz;
        mb[3] = c00*id;  mb[4] = c01*id;             mb[5] = c02*id;
        mb[6] = c01*id;  mb[7] = (a_*f_ - c_*c_)*id; mb[8] = (b_*c_ - a_*e_)*id;
        mb[9] = c02*id;  mb[10] = (b_*c_ - a_*e_)*id; mb[11] = (a_*d_ - b_*b_)*id;
    }
    __syncthreads();
    const int ar = a0 + (t >> 3), l8 = t & 7;
    const float Pbx = mb[0], Pby = mb[1], Pbz = mb[2];
    const float* Rrow = R + (size_t)(b * NPTS + ar) * NPTS;
    float v0 = 0.f, v1 = 0.f, v2 = 0.f;
    #pragma unroll 4
    for (int k = 0; k < 32; ++k) {
        int n = l8 + (k << 3);
        float Rv = Rrow[n];
        float cc = sq[n] - Rv * Rv;
        v0 = fmaf(cc, apx[n] - Pbx, v0);
        v1 = fmaf(cc, apy[n] - Pby, v1);
        v2 = fmaf(cc, apz[n] - Pbz, v2);
    }
    #pragma unroll
    for (int m = 1; m < 8; m <<= 1) {
        v0 += __shfl_xor(v0, m, 64);
        v1 += __shfl_xor(v1, m, 64);
        v2 += __shfl_xor(v2, m, 64);
    }
    if (l8 == 0) {
        const float sc = 0.5f / 256.f;
        v0 *= sc; v1 *= sc; v2 *= sc;
        float p0 = mb[3]*v0 + mb[4]*v1 + mb[5]*v2;
        float p1 = mb[6]*v0 + mb[7]*v1 + mb[8]*v2;
        float p2 = mb[9]*v0 + mb[10]*v1 + mb[11]*v2;
        float f0 = p0 - action_pts[b * 768 + ar];
        float f1 = p1 - action_pts[b * 768 + 256 + ar];
        float f2 = p2 - action_pts[b * 768 + 512 + ar];
        float wv = weight[b * NPTS + ar];
        out[b * 1024 + ar]              = f0;
        out[b * 1024 + 256 + ar]        = f1;
        out[b * 1024 + 512 + ar]        = f2;
        out[b * 1024 + 768 + ar]        = wv;
        out[2048 + b * 768 + ar]        = f0;
        out[2048 + b * 768 + 256 + ar]  = f1;
        out[2048 + b * 768 + 512 + ar]  = f2;
        out[3584 + b * 768 + ar]        = p0;
        out[3584 + b * 768 + 256 + ar]  = p1;
        out[3584 + b * 768 + 512 + ar]  = p2;
    }
}

extern "C" void kernel_launch(void* const* d_in, const int* in_sizes, int n_in,
                              void* d_out, int out_size, void* d_ws, size_t ws_size,
                              hipStream_t stream)
{
    const float* embA       = (const float*)d_in[0];
    const float* embB       = (const float*)d_in[1];
    const float* action_pts = (const float*)d_in[2];
    const float* anchor_pts = (const float*)d_in[3];
    const float* kw1 = (const float*)d_in[4];
    const float* kb1 = (const float*)d_in[5];
    const float* kw2 = (const float*)d_in[6];
    const float* kb2 = (const float*)d_in[7];
    const float* kw3 = (const float*)d_in[8];
    const float* kb3 = (const float*)d_in[9];
    const float* pw0 = (const float*)d_in[10];
    const float* pb0 = (const float*)d_in[11];
    const float* pw1 = (const float*)d_in[12];
    const float* pb1 = (const float*)d_in[13];
    const float* pw2 = (const float*)d_in[14];
    const float* pb2 = (const float*)d_in[15];
    const float* pw3 = (const float*)d_in[16];
    const float* pb3 = (const float*)d_in[17];
    const float* pw4 = (const float*)d_in[18];
    const float* pb4 = (const float*)d_in[19];
    const float* headw = (const float*)d_in[20];
    char* wsb = (char*)d_ws;
    float* out = (float*)d_out;

    _Float16* ap    = (_Float16*)(wsb + OFF_AP);
    _Float16* kw2ff = (_Float16*)(wsb + OFF_KW2F);
    _Float16* pnw   = (_Float16*)(wsb + OFF_PNW);
    _Float16* kw1f  = (_Float16*)(wsb + OFF_KW1F);
    float*    R     = (float*)(wsb + OFF_R);
    float*    wgt   = (float*)(wsb + OFF_WGT);

    hipLaunchKernelGGL(k_prep, dim3(1868), dim3(256), 0, stream,
                       kw2, kw1, pw0, pw1, pw2, pw3, pw4, kw2ff, pnw, kw1f);
    hipLaunchKernelGGL(k_mid, dim3(16, 10), dim3(256), 0, stream,
                       embA, embB, kw1f, kb1, ap,
                       pnw, pb0, pb1, pb2, pb3, pb4, headw, wgt);
    hipLaunchKernelGGL(k_pair, dim3(16, 64, 2), dim3(256), 0, stream,
                       ap, kw2ff, kb2, kw3, kb3, R);
    hipLaunchKernelGGL(k_solve, dim3(8, 2), dim3(256), 0, stream,
                       R, anchor_pts, action_pts, wgt, out);
}

// Round 12
// 147.258 us; speedup vs baseline: 1.0490x; 1.0490x over previous
//
#include <hip/hip_runtime.h>
#include <math.h>

#define NPTS 256
#define FDIM 512
#define H1   300
#define KP   320    // padded K (H1 -> 320)
#define H2   100
#define NP   112    // padded N (H2 -> 112)

typedef _Float16 half8  __attribute__((ext_vector_type(8)));
typedef _Float16 half2v __attribute__((ext_vector_type(2)));
typedef float    floatx4 __attribute__((ext_vector_type(4)));

// ---- workspace layout (byte offsets) ----
#define OFF_AP    0          // ap f16 [4 j][2 b][256 n][320 k]   : 1,310,720 B
#define OFF_KW2F  1310720    // kw2 f16 B-frag order [10][7][64][8]: 71,680 B
#define OFF_PNW   1382400    // pointnet weights f16 frag order   :   229,376 B
#define OFF_KW1F  1611776    // kw1 f16 frag order [2][16][20][512]: 655,360 B
#define OFF_R     2267136    // R fp32 [2][256][256]              :   524,288 B
#define OFF_WGT   2791424    // weight fp32 [2][256]              :     2,048 B

// ============ prep: kw2 -> B-frag order; pn + kw1 weights -> B-frag order ============
__global__ __launch_bounds__(256) void k_prep(
    const float* __restrict__ kw2, const float* __restrict__ kw1,
    const float* __restrict__ pw0, const float* __restrict__ pw1,
    const float* __restrict__ pw2, const float* __restrict__ pw3,
    const float* __restrict__ pw4,
    _Float16* __restrict__ kw2ff, _Float16* __restrict__ pnw,
    _Float16* __restrict__ kw1f)
{
    int idx = blockIdx.x * 256 + threadIdx.x;
    if (idx < 35840) {                       // kw2ff [kc10][nt7][64][8]
        int e = idx & 7, lane = (idx >> 3) & 63, r = idx >> 9;   // r 0..69
        int nt = r % 7, kc = r / 7;
        int g = nt * 16 + (lane & 15);
        int k = kc * 32 + ((lane >> 4) << 3) + e;
        kw2ff[idx] = (_Float16)((g < H2 && k < H1) ? kw2[g * H1 + k] : 0.f);
        return;
    }
    int i = idx - 35840;
    if (i < 114688) {                        // pointnet frags
        const float* src; int K, NT, off;
        if      (i < 32768) { src = pw0; K = 512; NT = 4;  off = 0; }
        else if (i < 36864) { src = pw1; K = 64;  NT = 4;  off = 32768; }
        else if (i < 40960) { src = pw2; K = 64;  NT = 4;  off = 36864; }
        else if (i < 49152) { src = pw3; K = 64;  NT = 8;  off = 40960; }
        else                { src = pw4; K = 128; NT = 32; off = 49152; }
        int li = i - off;
        int e = li & 7, l = (li >> 3) & 63, r = li >> 9;
        int nt = r % NT, s = r / NT;
        int o = nt * 16 + (l & 15);
        int c = s * 32 + ((l >> 4) << 3) + e;
        pnw[i] = (_Float16)src[o * K + c];
        return;
    }
    i -= 114688;
    if (i < 327680) {                        // kw1 frags [half][s16][nt20][64][8]
        int e = i & 7, l = (i >> 3) & 63, r = i >> 9;     // r 0..639
        int nt = r % 20, s = (r / 20) & 15, half = r / 320;
        int h = nt * 16 + (l & 15);
        int c = s * 32 + ((l >> 4) << 3) + e;
        kw1f[i] = (_Float16)((h < H1) ? kw1[h * (2 * FDIM) + half * FDIM + c] : 0.f);
    }
}

// ============ merged mid kernel: blockIdx.y 0..7 -> apart GEMMs, 8..9 -> pointnet ========
#define XSTR 520
__global__ __launch_bounds__(256) void k_mid(
    const float* __restrict__ embA, const float* __restrict__ embB,
    const _Float16* __restrict__ kw1f, const float* __restrict__ kb1,
    _Float16* __restrict__ ap,
    const _Float16* __restrict__ pnw,
    const float* __restrict__ pb0, const float* __restrict__ pb1,
    const float* __restrict__ pb2, const float* __restrict__ pb3,
    const float* __restrict__ pb4, const float* __restrict__ headw,
    float* __restrict__ wgt)
{
    __shared__ __align__(16) _Float16 sX[16 * XSTR];
    __shared__ __align__(16) _Float16 sH[16][136];
    __shared__ float sVp[4][16];

    const int tid = threadIdx.x;
    const int wave = tid >> 6, lane = tid & 63;
    const int l15 = lane & 15, quad = lane >> 4;

    if (blockIdx.y < 8) {
        // ---------------- apart path ----------------
        const int ntile = blockIdx.x, jb = blockIdx.y;
        const int j = jb >> 1, b = jb & 1;
        const int n0 = ntile * 16;

        const float* emb = ((j < 2) ? embA : embB) + b * FDIM * NPTS;
        {
            const int n = tid & 15, fp = tid >> 4;
            const float* src = emb + n0 + n;
            _Float16* dst = &sX[n * XSTR];
            #pragma unroll
            for (int i = 0; i < 16; ++i) {
                int f = 2 * fp + 32 * i;
                float e0 = src[(size_t)f * NPTS];
                float e1 = src[(size_t)(f + 1) * NPTS];
                half2v hv; hv.x = (_Float16)e0; hv.y = (_Float16)e1;
                *reinterpret_cast<half2v*>(&dst[f]) = hv;
            }
        }

        const _Float16* wf = kw1f + (size_t)(j & 1) * 163840;
        floatx4 acc[5];
        #pragma unroll
        for (int q = 0; q < 5; ++q) acc[q] = (floatx4){0.f, 0.f, 0.f, 0.f};

        __syncthreads();

        const _Float16* arow = &sX[l15 * XSTR + quad * 8];
        #pragma unroll 4
        for (int s = 0; s < 16; ++s) {
            half8 af = *reinterpret_cast<const half8*>(&arow[s * 32]);
            const _Float16* wrow = wf + ((size_t)(s * 20 + wave * 5) * 64 + lane) * 8;
            #pragma unroll
            for (int q = 0; q < 5; ++q) {
                half8 bf = *reinterpret_cast<const half8*>(wrow + q * 512);
                acc[q] = __builtin_amdgcn_mfma_f32_16x16x32_f16(af, bf, acc[q], 0, 0, 0);
            }
        }

        const bool addb = (j < 2);
        _Float16* apb = ap + (size_t)jb * NPTS * KP;
        #pragma unroll
        for (int q = 0; q < 5; ++q) {
            int nt = wave * 5 + q;
            int h = nt * 16 + l15;
            float bv = (addb && h < H1) ? kb1[h] : 0.f;
            #pragma unroll
            for (int r = 0; r < 4; ++r) {
                int n = n0 + quad * 4 + r;
                apb[(size_t)n * KP + h] = (_Float16)(acc[q][r] + bv);
            }
        }
        return;
    }

    // ---------------- pointnet path ----------------
    const int n0 = blockIdx.x * 16, b = blockIdx.y - 8;

    {
        const int n = tid & 15, fp = tid >> 4;
        const float* src = embA + (size_t)b * FDIM * NPTS + n0 + n;
        _Float16* dst = &sX[n * XSTR];
        #pragma unroll
        for (int i = 0; i < 16; ++i) {
            int f = 2 * fp + 32 * i;
            float e0 = src[(size_t)f * NPTS];
            float e1 = src[(size_t)(f + 1) * NPTS];
            half2v hv; hv.x = (_Float16)e0; hv.y = (_Float16)e1;
            *reinterpret_cast<half2v*>(&dst[f]) = hv;
        }
    }
    __syncthreads();

    const _Float16* w0f = pnw;
    const _Float16* w1f = pnw + 32768;
    const _Float16* w2f = pnw + 36864;
    const _Float16* w3f = pnw + 40960;
    const _Float16* w4f = pnw + 49152;

    {
        const _Float16* arow = &sX[l15 * XSTR + quad * 8];
        floatx4 acc = (floatx4){0.f, 0.f, 0.f, 0.f};
        #pragma unroll 4
        for (int s = 0; s < 16; ++s) {
            half8 af = *reinterpret_cast<const half8*>(&arow[s * 32]);
            half8 bf = *reinterpret_cast<const half8*>(w0f + ((size_t)(s * 4 + wave) * 64 + lane) * 8);
            acc = __builtin_amdgcn_mfma_f32_16x16x32_f16(af, bf, acc, 0, 0, 0);
        }
        int o = wave * 16 + l15;
        float bv = pb0[o];
        #pragma unroll
        for (int r = 0; r < 4; ++r)
            sH[quad * 4 + r][o] = (_Float16)fmaxf(acc[r] + bv, 0.f);
    }
    __syncthreads();

    const _Float16* wfs[2] = {w1f, w2f};
    const float* pbs[2] = {pb1, pb2};
    #pragma unroll
    for (int layer = 0; layer < 2; ++layer) {
        half8 a0 = *reinterpret_cast<const half8*>(&sH[l15][quad * 8]);
        half8 a1 = *reinterpret_cast<const half8*>(&sH[l15][32 + quad * 8]);
        half8 b0 = *reinterpret_cast<const half8*>(wfs[layer] + ((size_t)(wave) * 64 + lane) * 8);
        half8 b1 = *reinterpret_cast<const half8*>(wfs[layer] + ((size_t)(4 + wave) * 64 + lane) * 8);
        floatx4 ac = __builtin_amdgcn_mfma_f32_16x16x32_f16(a0, b0, (floatx4){0.f,0.f,0.f,0.f}, 0, 0, 0);
        ac = __builtin_amdgcn_mfma_f32_16x16x32_f16(a1, b1, ac, 0, 0, 0);
        __syncthreads();
        int o = wave * 16 + l15;
        float bv = pbs[layer][o];
        #pragma unroll
        for (int r = 0; r < 4; ++r)
            sH[quad * 4 + r][o] = (_Float16)fmaxf(ac[r] + bv, 0.f);
        __syncthreads();
    }

    {
        half8 a0 = *reinterpret_cast<const half8*>(&sH[l15][quad * 8]);
        half8 a1 = *reinterpret_cast<const half8*>(&sH[l15][32 + quad * 8]);
        floatx4 ac[2];
        #pragma unroll
        for (int q = 0; q < 2; ++q) {
            int nt = 2 * wave + q;
            half8 b0 = *reinterpret_cast<const half8*>(w3f + ((size_t)nt * 64 + lane) * 8);
            half8 b1 = *reinterpret_cast<const half8*>(w3f + ((size_t)(8 + nt) * 64 + lane) * 8);
            ac[q] = __builtin_amdgcn_mfma_f32_16x16x32_f16(a0, b0, (floatx4){0.f,0.f,0.f,0.f}, 0, 0, 0);
            ac[q] = __builtin_amdgcn_mfma_f32_16x16x32_f16(a1, b1, ac[q], 0, 0, 0);
        }
        __syncthreads();
        #pragma unroll
        for (int q = 0; q < 2; ++q) {
            int o = (2 * wave + q) * 16 + l15;
            float bv = pb3[o];
            #pragma unroll
            for (int r = 0; r < 4; ++r)
                sH[quad * 4 + r][o] = (_Float16)fmaxf(ac[q][r] + bv, 0.f);
        }
        __syncthreads();
    }

    half8 a4[4];
    #pragma unroll
    for (int s = 0; s < 4; ++s)
        a4[s] = *reinterpret_cast<const half8*>(&sH[l15][s * 32 + quad * 8]);
    float ps0 = 0.f, ps1 = 0.f, ps2 = 0.f, ps3 = 0.f;
    #pragma unroll 2
    for (int q = 0; q < 8; ++q) {
        int nt = wave * 8 + q;
        floatx4 a = (floatx4){0.f, 0.f, 0.f, 0.f};
        #pragma unroll
        for (int s = 0; s < 4; ++s) {
            half8 bf = *reinterpret_cast<const half8*>(w4f + ((size_t)(s * 32 + nt) * 64 + lane) * 8);
            a = __builtin_amdgcn_mfma_f32_16x16x32_f16(a4[s], bf, a, 0, 0, 0);
        }
        int o = nt * 16 + l15;
        float hwv = headw[o], b4v = pb4[o];
        ps0 = fmaf(hwv, fmaxf(a[0] + b4v, 0.f), ps0);
        ps1 = fmaf(hwv, fmaxf(a[1] + b4v, 0.f), ps1);
        ps2 = fmaf(hwv, fmaxf(a[2] + b4v, 0.f), ps2);
        ps3 = fmaf(hwv, fmaxf(a[3] + b4v, 0.f), ps3);
    }
    #pragma unroll
    for (int m = 1; m < 16; m <<= 1) {
        ps0 += __shfl_xor(ps0, m, 64);
        ps1 += __shfl_xor(ps1, m, 64);
        ps2 += __shfl_xor(ps2, m, 64);
        ps3 += __shfl_xor(ps3, m, 64);
    }
    if (l15 == 0) {
        sVp[wave][quad * 4 + 0] = ps0;
        sVp[wave][quad * 4 + 1] = ps1;
        sVp[wave][quad * 4 + 2] = ps2;
        sVp[wave][quad * 4 + 3] = ps3;
    }
    __syncthreads();
    if (tid < 16) {
        float s = sVp[0][tid] + sVp[1][tid] + sVp[2][tid] + sVp[3][tid];
        wgt[(size_t)b * NPTS + n0 + tid] = s;
    }
}

// ============ Kernel B: pair tail — R10 structure, launch_bounds (256,3) for MLP headroom ==
// acc[2][7]/wave, 8 tiles/block, grid (16 mt, 64 nt, 2 b). 3 blocks/CU with ~170 VGPR
// budget so all 7 kw2ff dwordx4 loads per kc can stay in flight (was reg-choked at 88).
#define SA_STR 328
__global__ __launch_bounds__(256, 3) void k_pair(
    const _Float16* __restrict__ ap, const _Float16* __restrict__ kw2ff,
    const float* __restrict__ kb2, const float* __restrict__ kw3,
    const float* __restrict__ kb3, float* __restrict__ R)
{
    const int mt = blockIdx.x, nt = blockIdx.y, b = blockIdx.z;
    const int m0 = mt * 16, n0 = nt * 4;
    __shared__ __align__(16) _Float16 sA[8 * SA_STR];        // a1/a2 rows (4 each), 5.1 KB
    __shared__ __align__(16) _Float16 sBT[2 * 10 * 64 * 8];  // b-frags, 20 KB
    __shared__ float sV[128];
    const int tid = threadIdx.x;
    const int wave = tid >> 6, lane = tid & 63;
    const int l15 = lane & 15, quad = lane >> 4;

    // ---- stage a-rows [t2][4 n][320] : t0=a1, t1=a2 ----
    for (int idx = tid; idx < 320; idx += 256) {
        int row = idx / 40, col = (idx - row * 40) * 8;
        int t = row >> 2, r = row & 3;
        half8 v = *reinterpret_cast<const half8*>(
            &ap[(size_t)((t * 2 + b) * NPTS + n0 + r) * KP + col]);
        *reinterpret_cast<half8*>(&sA[row * SA_STR + col]) = v;
    }
    // ---- stage b-rows in frag order: sBT[t][kc][lane][8] ; t0<-b2(j3), t1<-b1(j2) ----
    for (int idx = tid; idx < 1280; idx += 256) {
        int ln = idx & 63, kc = (idx >> 6) % 10, t = idx / 640;
        int j = t ? 2 : 3;
        half8 v = *reinterpret_cast<const half8*>(
            &ap[(size_t)((j * 2 + b) * NPTS + m0 + (ln & 15)) * KP + kc * 32 + ((ln >> 4) << 3)]);
        *reinterpret_cast<half8*>(&sBT[(size_t)idx * 8]) = v;
    }
    __syncthreads();   // only barrier before epilogue

    const int tail = wave >> 1;
    const _Float16* sBTt = &sBT[(size_t)tail * 10 * 64 * 8 + (size_t)lane * 8];
    const _Float16* aRow0 = &sA[(size_t)(tail * 4 + (wave & 1) * 2) * SA_STR + quad * 8];
    const _Float16* kwf = kw2ff + (size_t)lane * 8;

    floatx4 acc[2][7];
    #pragma unroll
    for (int i = 0; i < 2; ++i)
        #pragma unroll
        for (int jj = 0; jj < 7; ++jj)
            acc[i][jj] = (floatx4){0.f, 0.f, 0.f, 0.f};

    for (int kc = 0; kc < 10; ++kc) {
        half8 bfrag = *reinterpret_cast<const half8*>(&sBTt[(size_t)kc * 64 * 8]);
        half8 af[2];
        #pragma unroll
        for (int i = 0; i < 2; ++i) {
            half8 av = *reinterpret_cast<const half8*>(&aRow0[i * SA_STR + kc * 32]);
            half8 s = av + bfrag;
            half8 rv;
            #pragma unroll
            for (int e = 0; e < 8; ++e)
                rv[e] = s[e] > (_Float16)0 ? s[e] : (_Float16)0;
            af[i] = rv;
        }
        #pragma unroll
        for (int jj = 0; jj < 7; ++jj) {
            half8 bw = *reinterpret_cast<const half8*>(&kwf[(size_t)(kc * 7 + jj) * 64 * 8]);
            acc[0][jj] = __builtin_amdgcn_mfma_f32_16x16x32_f16(af[0], bw, acc[0][jj], 0, 0, 0);
            acc[1][jj] = __builtin_amdgcn_mfma_f32_16x16x32_f16(af[1], bw, acc[1][jj], 0, 0, 0);
        }
    }

    // ---- epilogue: bias+relu layer2, dot kw3, reduce over g(l15), combine tails ----
    float kw3v[7], kb2v[7];
    #pragma unroll
    for (int jj = 0; jj < 7; ++jj) {
        int g = jj * 16 + l15;
        kw3v[jj] = (g < H2) ? kw3[g] : 0.f;
        kb2v[jj] = (g < H2) ? kb2[g] : 0.f;
    }
    #pragma unroll
    for (int i = 0; i < 2; ++i) {
        float rv0 = 0.f, rv1 = 0.f, rv2 = 0.f, rv3 = 0.f;
        #pragma unroll
        for (int jj = 0; jj < 7; ++jj) {
            float w3 = kw3v[jj], b2 = kb2v[jj];
            rv0 = fmaf(w3, fmaxf(acc[i][jj][0] + b2, 0.f), rv0);
            rv1 = fmaf(w3, fmaxf(acc[i][jj][1] + b2, 0.f), rv1);
            rv2 = fmaf(w3, fmaxf(acc[i][jj][2] + b2, 0.f), rv2);
            rv3 = fmaf(w3, fmaxf(acc[i][jj][3] + b2, 0.f), rv3);
        }
        #pragma unroll
        for (int m = 1; m < 16; m <<= 1) {
            rv0 += __shfl_xor(rv0, m, 64);
            rv1 += __shfl_xor(rv1, m, 64);
            rv2 += __shfl_xor(rv2, m, 64);
            rv3 += __shfl_xor(rv3, m, 64);
        }
        if (l15 == 0) {
            int base = (tail * 4 + (wave & 1) * 2 + i) * 16 + quad * 4;
            sV[base + 0] = rv0; sV[base + 1] = rv1;
            sV[base + 2] = rv2; sV[base + 3] = rv3;
        }
    }
    __syncthreads();
    if (tid < 64) {
        float s = 0.5f * (sV[tid] + sV[64 + tid]) + kb3[0];
        float sp = fmaxf(s, 0.f) + log1pf(expf(-fabsf(s)));
        int n_l = tid >> 4, m_l = tid & 15;
        R[(size_t)(b * NPTS + n0 + n_l) * NPTS + m0 + m_l] = sp;
    }
}

// ============ fused multilateration setup + solve + epilogue ============
__global__ __launch_bounds__(256) void k_solve(
    const float* __restrict__ R, const float* __restrict__ anchor_pts,
    const float* __restrict__ action_pts, const float* __restrict__ weight,
    float* __restrict__ out)
{
    const int a0 = blockIdx.x * 32, b = blockIdx.y;
    __shared__ float apx[256], apy[256], apz[256], sq[256];
    __shared__ float red[256];
    __shared__ float mb[12];
    const int t = threadIdx.x;
    const float px = anchor_pts[b * 768 + t];
    const float py = anchor_pts[b * 768 + 256 + t];
    const float pz = anchor_pts[b * 768 + 512 + t];
    apx[t] = px; apy[t] = py; apz[t] = pz;
    sq[t] = px * px + py * py + pz * pz;
    float sums[9];
    {
        float vals[9] = {px, py, pz, px*px, px*py, px*pz, py*py, py*pz, pz*pz};
        #pragma unroll
        for (int k = 0; k < 9; ++k) {
            red[t] = vals[k]; __syncthreads();
            for (int s = 128; s > 0; s >>= 1) {
                if (t < s) red[t] += red[t + s];
                __syncthreads();
            }
            sums[k] = red[0]; __syncthreads();
        }
    }
    if (t == 0) {
        const float inv = 1.f / 256.f;
        float mx = sums[0]*inv, my = sums[1]*inv, mz = sums[2]*inv;
        float a_ = sums[3]*inv - mx*mx;
        float b_ = sums[4]*inv - mx*my;
        float c_ = sums[5]*inv - mx*mz;
        float d_ = sums[6]*inv - my*my;
        float e_ = sums[7]*inv - my*mz;
        float f_ = sums[8]*inv - mz*mz;
        float c00 = d_*f_ - e_*e_;
        float c01 = c_*e_ - b_*f_;
        float c02 = b_*e_ - c_*d_;
        float det = a_*c00 + b_*c01 + c_*c02;
        float id = 1.f / det;
        mb[0] = mx; mb[1] = my; mb[2] = mz;
        mb[3] = c00*id;  mb[4] = c01*id;             mb[5] = c02*id;
        mb[6] = c01*id;  mb[7] = (a_*f_ - c_*c_)*id; mb[8] = (b_*c_ - a_*e_)*id;
        mb[9] = c02*id;  mb[10] = (b_*c_ - a_*e_)*id; mb[11] = (a_*d_ - b_*b_)*id;
    }
    __syncthreads();
    const int ar = a0 + (t >> 3), l8 = t & 7;
    const float Pbx = mb[0], Pby = mb[1], Pbz = mb[2];
    const float* Rrow = R + (size_t)(b * NPTS + ar) * NPTS;
    float v0 = 0.f, v1 = 0.f, v2 = 0.f;
    #pragma unroll 4
    for (int k = 0; k < 32; ++k) {
        int n = l8 + (k << 3);
        float Rv = Rrow[n];
        float cc = sq[n] - Rv * Rv;
        v0 = fmaf(cc, apx[n] - Pbx, v0);
        v1 = fmaf(cc, apy[n] - Pby, v1);
        v2 = fmaf(cc, apz[n] - Pbz, v2);
    }
    #pragma unroll
    for (int m = 1; m < 8; m <<= 1) {
        v0 += __shfl_xor(v0, m, 64);
        v1 += __shfl_xor(v1, m, 64);
        v2 += __shfl_xor(v2, m, 64);
    }
    if (l8 == 0) {
        const float sc = 0.5f / 256.f;
        v0 *= sc; v1 *= sc; v2 *= sc;
        float p0 = mb[3]*v0 + mb[4]*v1 + mb[5]*v2;
        float p1 = mb[6]*v0 + mb[7]*v1 + mb[8]*v2;
        float p2 = mb[9]*v0 + mb[10]*v1 + mb[11]*v2;
        float f0 = p0 - action_pts[b * 768 + ar];
        float f1 = p1 - action_pts[b * 768 + 256 + ar];
        float f2 = p2 - action_pts[b * 768 + 512 + ar];
        float wv = weight[b * NPTS + ar];
        out[b * 1024 + ar]              = f0;
        out[b * 1024 + 256 + ar]        = f1;
        out[b * 1024 + 512 + ar]        = f2;
        out[b * 1024 + 768 + ar]        = wv;
        out[2048 + b * 768 + ar]        = f0;
        out[2048 + b * 768 + 256 + ar]  = f1;
        out[2048 + b * 768 + 512 + ar]  = f2;
        out[3584 + b * 768 + ar]        = p0;
        out[3584 + b * 768 + 256 + ar]  = p1;
        out[3584 + b * 768 + 512 + ar]  = p2;
    }
}

extern "C" void kernel_launch(void* const* d_in, const int* in_sizes, int n_in,
                              void* d_out, int out_size, void* d_ws, size_t ws_size,
                              hipStream_t stream)
{
    const float* embA       = (const float*)d_in[0];
    const float* embB       = (const float*)d_in[1];
    const float* action_pts = (const float*)d_in[2];
    const float* anchor_pts = (const float*)d_in[3];
    const float* kw1 = (const float*)d_in[4];
    const float* kb1 = (const float*)d_in[5];
    const float* kw2 = (const float*)d_in[6];
    const float* kb2 = (const float*)d_in[7];
    const float* kw3 = (const float*)d_in[8];
    const float* kb3 = (const float*)d_in[9];
    const float* pw0 = (const float*)d_in[10];
    const float* pb0 = (const float*)d_in[11];
    const float* pw1 = (const float*)d_in[12];
    const float* pb1 = (const float*)d_in[13];
    const float* pw2 = (const float*)d_in[14];
    const float* pb2 = (const float*)d_in[15];
    const float* pw3 = (const float*)d_in[16];
    const float* pb3 = (const float*)d_in[17];
    const float* pw4 = (const float*)d_in[18];
    const float* pb4 = (const float*)d_in[19];
    const float* headw = (const float*)d_in[20];
    char* wsb = (char*)d_ws;
    float* out = (float*)d_out;

    _Float16* ap    = (_Float16*)(wsb + OFF_AP);
    _Float16* kw2ff = (_Float16*)(wsb + OFF_KW2F);
    _Float16* pnw   = (_Float16*)(wsb + OFF_PNW);
    _Float16* kw1f  = (_Float16*)(wsb + OFF_KW1F);
    float*    R     = (float*)(wsb + OFF_R);
    float*    wgt   = (float*)(wsb + OFF_WGT);

    hipLaunchKernelGGL(k_prep, dim3(1868), dim3(256), 0, stream,
                       kw2, kw1, pw0, pw1, pw2, pw3, pw4, kw2ff, pnw, kw1f);
    hipLaunchKernelGGL(k_mid, dim3(16, 10), dim3(256), 0, stream,
                       embA, embB, kw1f, kb1, ap,
                       pnw, pb0, pb1, pb2, pb3, pb4, headw, wgt);
    hipLaunchKernelGGL(k_pair, dim3(16, 64, 2), dim3(256), 0, stream,
                       ap, kw2ff, kb2, kw3, kb3, R);
    hipLaunchKernelGGL(k_solve, dim3(8, 2), dim3(256), 0, stream,
                       R, anchor_pts, action_pts, wgt, out);
}

// Round 13
// 146.428 us; speedup vs baseline: 1.0549x; 1.0057x over previous
//
#include <hip/hip_runtime.h>
#include <math.h>

#define NPTS 256
#define FDIM 512
#define H1   300
#define KP   320    // padded K (H1 -> 320)
#define H2   100
#define NP   112    // padded N (H2 -> 112)

typedef _Float16 half8  __attribute__((ext_vector_type(8)));
typedef _Float16 half2v __attribute__((ext_vector_type(2)));
typedef float    floatx4 __attribute__((ext_vector_type(4)));

// ---- workspace layout (byte offsets) ----
#define OFF_AP    0          // ap f16 [4 j][2 b][256 n][320 k]   : 1,310,720 B
#define OFF_KW2F  1310720    // kw2 f16 B-frag order [10][7][64][8]: 71,680 B
#define OFF_PNW   1382400    // pointnet weights f16 frag order   :   229,376 B
#define OFF_KW1F  1611776    // kw1 f16 frag order [2][16][20][512]: 655,360 B
#define OFF_R     2267136    // R fp32 [2][256][256]              :   524,288 B
#define OFF_WGT   2791424    // weight fp32 [2][256]              :     2,048 B

// ============ prep: kw2 -> B-frag order; pn + kw1 weights -> B-frag order ============
__global__ __launch_bounds__(256) void k_prep(
    const float* __restrict__ kw2, const float* __restrict__ kw1,
    const float* __restrict__ pw0, const float* __restrict__ pw1,
    const float* __restrict__ pw2, const float* __restrict__ pw3,
    const float* __restrict__ pw4,
    _Float16* __restrict__ kw2ff, _Float16* __restrict__ pnw,
    _Float16* __restrict__ kw1f)
{
    int idx = blockIdx.x * 256 + threadIdx.x;
    if (idx < 35840) {                       // kw2ff [kc10][nt7][64][8]
        int e = idx & 7, lane = (idx >> 3) & 63, r = idx >> 9;   // r 0..69
        int nt = r % 7, kc = r / 7;
        int g = nt * 16 + (lane & 15);
        int k = kc * 32 + ((lane >> 4) << 3) + e;
        kw2ff[idx] = (_Float16)((g < H2 && k < H1) ? kw2[g * H1 + k] : 0.f);
        return;
    }
    int i = idx - 35840;
    if (i < 114688) {                        // pointnet frags
        const float* src; int K, NT, off;
        if      (i < 32768) { src = pw0; K = 512; NT = 4;  off = 0; }
        else if (i < 36864) { src = pw1; K = 64;  NT = 4;  off = 32768; }
        else if (i < 40960) { src = pw2; K = 64;  NT = 4;  off = 36864; }
        else if (i < 49152) { src = pw3; K = 64;  NT = 8;  off = 40960; }
        else                { src = pw4; K = 128; NT = 32; off = 49152; }
        int li = i - off;
        int e = li & 7, l = (li >> 3) & 63, r = li >> 9;
        int nt = r % NT, s = r / NT;
        int o = nt * 16 + (l & 15);
        int c = s * 32 + ((l >> 4) << 3) + e;
        pnw[i] = (_Float16)src[o * K + c];
        return;
    }
    i -= 114688;
    if (i < 327680) {                        // kw1 frags [half][s16][nt20][64][8]
        int e = i & 7, l = (i >> 3) & 63, r = i >> 9;     // r 0..639
        int nt = r % 20, s = (r / 20) & 15, half = r / 320;
        int h = nt * 16 + (l & 15);
        int c = s * 32 + ((l >> 4) << 3) + e;
        kw1f[i] = (_Float16)((h < H1) ? kw1[h * (2 * FDIM) + half * FDIM + c] : 0.f);
    }
}

// ============ merged mid kernel: blockIdx.y 0..7 -> apart GEMMs, 8..9 -> pointnet ========
#define XSTR 520
__global__ __launch_bounds__(256) void k_mid(
    const float* __restrict__ embA, const float* __restrict__ embB,
    const _Float16* __restrict__ kw1f, const float* __restrict__ kb1,
    _Float16* __restrict__ ap,
    const _Float16* __restrict__ pnw,
    const float* __restrict__ pb0, const float* __restrict__ pb1,
    const float* __restrict__ pb2, const float* __restrict__ pb3,
    const float* __restrict__ pb4, const float* __restrict__ headw,
    float* __restrict__ wgt)
{
    __shared__ __align__(16) _Float16 sX[16 * XSTR];
    __shared__ __align__(16) _Float16 sH[16][136];
    __shared__ float sVp[4][16];

    const int tid = threadIdx.x;
    const int wave = tid >> 6, lane = tid & 63;
    const int l15 = lane & 15, quad = lane >> 4;

    if (blockIdx.y < 8) {
        // ---------------- apart path ----------------
        const int ntile = blockIdx.x, jb = blockIdx.y;
        const int j = jb >> 1, b = jb & 1;
        const int n0 = ntile * 16;

        const float* emb = ((j < 2) ? embA : embB) + b * FDIM * NPTS;
        {
            const int n = tid & 15, fp = tid >> 4;
            const float* src = emb + n0 + n;
            _Float16* dst = &sX[n * XSTR];
            #pragma unroll
            for (int i = 0; i < 16; ++i) {
                int f = 2 * fp + 32 * i;
                float e0 = src[(size_t)f * NPTS];
                float e1 = src[(size_t)(f + 1) * NPTS];
                half2v hv; hv.x = (_Float16)e0; hv.y = (_Float16)e1;
                *reinterpret_cast<half2v*>(&dst[f]) = hv;
            }
        }

        const _Float16* wf = kw1f + (size_t)(j & 1) * 163840;
        floatx4 acc[5];
        #pragma unroll
        for (int q = 0; q < 5; ++q) acc[q] = (floatx4){0.f, 0.f, 0.f, 0.f};

        __syncthreads();

        const _Float16* arow = &sX[l15 * XSTR + quad * 8];
        #pragma unroll 4
        for (int s = 0; s < 16; ++s) {
            half8 af = *reinterpret_cast<const half8*>(&arow[s * 32]);
            const _Float16* wrow = wf + ((size_t)(s * 20 + wave * 5) * 64 + lane) * 8;
            #pragma unroll
            for (int q = 0; q < 5; ++q) {
                half8 bf = *reinterpret_cast<const half8*>(wrow + q * 512);
                acc[q] = __builtin_amdgcn_mfma_f32_16x16x32_f16(af, bf, acc[q], 0, 0, 0);
            }
        }

        const bool addb = (j < 2);
        _Float16* apb = ap + (size_t)jb * NPTS * KP;
        #pragma unroll
        for (int q = 0; q < 5; ++q) {
            int nt = wave * 5 + q;
            int h = nt * 16 + l15;
            float bv = (addb && h < H1) ? kb1[h] : 0.f;
            #pragma unroll
            for (int r = 0; r < 4; ++r) {
                int n = n0 + quad * 4 + r;
                apb[(size_t)n * KP + h] = (_Float16)(acc[q][r] + bv);
            }
        }
        return;
    }

    // ---------------- pointnet path ----------------
    const int n0 = blockIdx.x * 16, b = blockIdx.y - 8;

    {
        const int n = tid & 15, fp = tid >> 4;
        const float* src = embA + (size_t)b * FDIM * NPTS + n0 + n;
        _Float16* dst = &sX[n * XSTR];
        #pragma unroll
        for (int i = 0; i < 16; ++i) {
            int f = 2 * fp + 32 * i;
            float e0 = src[(size_t)f * NPTS];
            float e1 = src[(size_t)(f + 1) * NPTS];
            half2v hv; hv.x = (_Float16)e0; hv.y = (_Float16)e1;
            *reinterpret_cast<half2v*>(&dst[f]) = hv;
        }
    }
    __syncthreads();

    const _Float16* w0f = pnw;
    const _Float16* w1f = pnw + 32768;
    const _Float16* w2f = pnw + 36864;
    const _Float16* w3f = pnw + 40960;
    const _Float16* w4f = pnw + 49152;

    {
        const _Float16* arow = &sX[l15 * XSTR + quad * 8];
        floatx4 acc = (floatx4){0.f, 0.f, 0.f, 0.f};
        #pragma unroll 4
        for (int s = 0; s < 16; ++s) {
            half8 af = *reinterpret_cast<const half8*>(&arow[s * 32]);
            half8 bf = *reinterpret_cast<const half8*>(w0f + ((size_t)(s * 4 + wave) * 64 + lane) * 8);
            acc = __builtin_amdgcn_mfma_f32_16x16x32_f16(af, bf, acc, 0, 0, 0);
        }
        int o = wave * 16 + l15;
        float bv = pb0[o];
        #pragma unroll
        for (int r = 0; r < 4; ++r)
            sH[quad * 4 + r][o] = (_Float16)fmaxf(acc[r] + bv, 0.f);
    }
    __syncthreads();

    const _Float16* wfs[2] = {w1f, w2f};
    const float* pbs[2] = {pb1, pb2};
    #pragma unroll
    for (int layer = 0; layer < 2; ++layer) {
        half8 a0 = *reinterpret_cast<const half8*>(&sH[l15][quad * 8]);
        half8 a1 = *reinterpret_cast<const half8*>(&sH[l15][32 + quad * 8]);
        half8 b0 = *reinterpret_cast<const half8*>(wfs[layer] + ((size_t)(wave) * 64 + lane) * 8);
        half8 b1 = *reinterpret_cast<const half8*>(wfs[layer] + ((size_t)(4 + wave) * 64 + lane) * 8);
        floatx4 ac = __builtin_amdgcn_mfma_f32_16x16x32_f16(a0, b0, (floatx4){0.f,0.f,0.f,0.f}, 0, 0, 0);
        ac = __builtin_amdgcn_mfma_f32_16x16x32_f16(a1, b1, ac, 0, 0, 0);
        __syncthreads();
        int o = wave * 16 + l15;
        float bv = pbs[layer][o];
        #pragma unroll
        for (int r = 0; r < 4; ++r)
            sH[quad * 4 + r][o] = (_Float16)fmaxf(ac[r] + bv, 0.f);
        __syncthreads();
    }

    {
        half8 a0 = *reinterpret_cast<const half8*>(&sH[l15][quad * 8]);
        half8 a1 = *reinterpret_cast<const half8*>(&sH[l15][32 + quad * 8]);
        floatx4 ac[2];
        #pragma unroll
        for (int q = 0; q < 2; ++q) {
            int nt = 2 * wave + q;
            half8 b0 = *reinterpret_cast<const half8*>(w3f + ((size_t)nt * 64 + lane) * 8);
            half8 b1 = *reinterpret_cast<const half8*>(w3f + ((size_t)(8 + nt) * 64 + lane) * 8);
            ac[q] = __builtin_amdgcn_mfma_f32_16x16x32_f16(a0, b0, (floatx4){0.f,0.f,0.f,0.f}, 0, 0, 0);
            ac[q] = __builtin_amdgcn_mfma_f32_16x16x32_f16(a1, b1, ac[q], 0, 0, 0);
        }
        __syncthreads();
        #pragma unroll
        for (int q = 0; q < 2; ++q) {
            int o = (2 * wave + q) * 16 + l15;
            float bv = pb3[o];
            #pragma unroll
            for (int r = 0; r < 4; ++r)
                sH[quad * 4 + r][o] = (_Float16)fmaxf(ac[q][r] + bv, 0.f);
        }
        __syncthreads();
    }

    half8 a4[4];
    #pragma unroll
    for (int s = 0; s < 4; ++s)
        a4[s] = *reinterpret_cast<const half8*>(&sH[l15][s * 32 + quad * 8]);
    float ps0 = 0.f, ps1 = 0.f, ps2 = 0.f, ps3 = 0.f;
    #pragma unroll 2
    for (int q = 0; q < 8; ++q) {
        int nt = wave * 8 + q;
        floatx4 a = (floatx4){0.f, 0.f, 0.f, 0.f};
        #pragma unroll
        for (int s = 0; s < 4; ++s) {
            half8 bf = *reinterpret_cast<const half8*>(w4f + ((size_t)(s * 32 + nt) * 64 + lane) * 8);
            a = __builtin_amdgcn_mfma_f32_16x16x32_f16(a4[s], bf, a, 0, 0, 0);
        }
        int o = nt * 16 + l15;
        float hwv = headw[o], b4v = pb4[o];
        ps0 = fmaf(hwv, fmaxf(a[0] + b4v, 0.f), ps0);
        ps1 = fmaf(hwv, fmaxf(a[1] + b4v, 0.f), ps1);
        ps2 = fmaf(hwv, fmaxf(a[2] + b4v, 0.f), ps2);
        ps3 = fmaf(hwv, fmaxf(a[3] + b4v, 0.f), ps3);
    }
    #pragma unroll
    for (int m = 1; m < 16; m <<= 1) {
        ps0 += __shfl_xor(ps0, m, 64);
        ps1 += __shfl_xor(ps1, m, 64);
        ps2 += __shfl_xor(ps2, m, 64);
        ps3 += __shfl_xor(ps3, m, 64);
    }
    if (l15 == 0) {
        sVp[wave][quad * 4 + 0] = ps0;
        sVp[wave][quad * 4 + 1] = ps1;
        sVp[wave][quad * 4 + 2] = ps2;
        sVp[wave][quad * 4 + 3] = ps3;
    }
    __syncthreads();
    if (tid < 16) {
        float s = sVp[0][tid] + sVp[1][tid] + sVp[2][tid] + sVp[3][tid];
        wgt[(size_t)b * NPTS + n0 + tid] = s;
    }
}

// ============ Kernel B: pair tail — chunked LDS kw2 staging at 4 blocks/CU ============
// R10 tile mapping (acc[2][7]/wave, 8 tiles/block, grid (16,64,2)). kw2 staged in a
// 2-kc (14 KB) LDS buffer, register-prefetched one chunk ahead (outside the kc loop).
// Total LDS 40,576 B -> 4 blocks/CU preserved; kw2ff read once per block (4x less L2).
#define SA_STR 328
__global__ __launch_bounds__(256, 4) void k_pair(
    const _Float16* __restrict__ ap, const _Float16* __restrict__ kw2ff,
    const float* __restrict__ kb2, const float* __restrict__ kw3,
    const float* __restrict__ kb3, float* __restrict__ R)
{
    const int mt = blockIdx.x, nt = blockIdx.y, b = blockIdx.z;
    const int m0 = mt * 16, n0 = nt * 4;
    __shared__ __align__(16) _Float16 sA[8 * SA_STR];        // 5,248 B
    __shared__ __align__(16) _Float16 sBT[2 * 10 * 64 * 8];  // 20,480 B
    __shared__ __align__(16) _Float16 sW[2 * 7 * 64 * 8];    // 14,336 B (2 kc chunk)
    __shared__ float sV[128];                                // 512 B
    const int tid = threadIdx.x;
    const int wave = tid >> 6, lane = tid & 63;
    const int l15 = lane & 15, quad = lane >> 4;

    // ---- stage a-rows [t2][4 n][320] ----
    for (int idx = tid; idx < 320; idx += 256) {
        int row = idx / 40, col = (idx - row * 40) * 8;
        int t = row >> 2, r = row & 3;
        half8 v = *reinterpret_cast<const half8*>(
            &ap[(size_t)((t * 2 + b) * NPTS + n0 + r) * KP + col]);
        *reinterpret_cast<half8*>(&sA[row * SA_STR + col]) = v;
    }
    // ---- stage b-rows in frag order: sBT[t][kc][lane][8] ----
    for (int idx = tid; idx < 1280; idx += 256) {
        int ln = idx & 63, kc = (idx >> 6) % 10, t = idx / 640;
        int j = t ? 2 : 3;
        half8 v = *reinterpret_cast<const half8*>(
            &ap[(size_t)((j * 2 + b) * NPTS + m0 + (ln & 15)) * KP + kc * 32 + ((ln >> 4) << 3)]);
        *reinterpret_cast<half8*>(&sBT[(size_t)idx * 8]) = v;
    }
    // ---- stage kw2 chunk 0 (kc 0,1) : 896 half8 ----
    for (int idx = tid; idx < 896; idx += 256)
        *reinterpret_cast<half8*>(&sW[(size_t)idx * 8]) =
            *reinterpret_cast<const half8*>(&kw2ff[(size_t)idx * 8]);
    __syncthreads();

    const int tail = wave >> 1;
    const _Float16* sBTt = &sBT[(size_t)tail * 10 * 64 * 8 + (size_t)lane * 8];
    const _Float16* aRow0 = &sA[(size_t)(tail * 4 + (wave & 1) * 2) * SA_STR + quad * 8];
    const _Float16* sWl = sW + (size_t)lane * 8;

    floatx4 acc[2][7];
    #pragma unroll
    for (int i = 0; i < 2; ++i)
        #pragma unroll
        for (int jj = 0; jj < 7; ++jj)
            acc[i][jj] = (floatx4){0.f, 0.f, 0.f, 0.f};

    // register prefetch of chunk 1
    half8 pre[4];
    #pragma unroll
    for (int q = 0; q < 4; ++q) {
        int idx = tid + q * 256;
        if (idx < 896)
            pre[q] = *reinterpret_cast<const half8*>(&kw2ff[(size_t)(896 + idx) * 8]);
    }

    for (int c = 0; c < 5; ++c) {
        // ---- compute kc = 2c, 2c+1 from sW (prefetch of c+1 in flight) ----
        #pragma unroll
        for (int kcL = 0; kcL < 2; ++kcL) {
            const int kc = 2 * c + kcL;
            half8 bfrag = *reinterpret_cast<const half8*>(&sBTt[(size_t)kc * 64 * 8]);
            half8 af[2];
            #pragma unroll
            for (int i = 0; i < 2; ++i) {
                half8 av = *reinterpret_cast<const half8*>(&aRow0[i * SA_STR + kc * 32]);
                half8 s = av + bfrag;
                half8 rv;
                #pragma unroll
                for (int e = 0; e < 8; ++e)
                    rv[e] = s[e] > (_Float16)0 ? s[e] : (_Float16)0;
                af[i] = rv;
            }
            #pragma unroll
            for (int jj = 0; jj < 7; ++jj) {
                half8 bw = *reinterpret_cast<const half8*>(&sWl[(size_t)(kcL * 7 + jj) * 64 * 8]);
                acc[0][jj] = __builtin_amdgcn_mfma_f32_16x16x32_f16(af[0], bw, acc[0][jj], 0, 0, 0);
                acc[1][jj] = __builtin_amdgcn_mfma_f32_16x16x32_f16(af[1], bw, acc[1][jj], 0, 0, 0);
            }
        }
        if (c < 4) {
            __syncthreads();   // all waves done reading sW chunk c
            #pragma unroll
            for (int q = 0; q < 4; ++q) {
                int idx = tid + q * 256;
                if (idx < 896)
                    *reinterpret_cast<half8*>(&sW[(size_t)idx * 8]) = pre[q];
            }
            if (c < 3) {
                #pragma unroll
                for (int q = 0; q < 4; ++q) {
                    int idx = tid + q * 256;
                    if (idx < 896)
                        pre[q] = *reinterpret_cast<const half8*>(
                            &kw2ff[(size_t)((c + 2) * 896 + idx) * 8]);
                }
            }
            __syncthreads();   // sW chunk c+1 visible
        }
    }

    // ---- epilogue: bias+relu layer2, dot kw3, reduce over g(l15), combine tails ----
    float kw3v[7], kb2v[7];
    #pragma unroll
    for (int jj = 0; jj < 7; ++jj) {
        int g = jj * 16 + l15;
        kw3v[jj] = (g < H2) ? kw3[g] : 0.f;
        kb2v[jj] = (g < H2) ? kb2[g] : 0.f;
    }
    #pragma unroll
    for (int i = 0; i < 2; ++i) {
        float rv0 = 0.f, rv1 = 0.f, rv2 = 0.f, rv3 = 0.f;
        #pragma unroll
        for (int jj = 0; jj < 7; ++jj) {
            float w3 = kw3v[jj], b2 = kb2v[jj];
            rv0 = fmaf(w3, fmaxf(acc[i][jj][0] + b2, 0.f), rv0);
            rv1 = fmaf(w3, fmaxf(acc[i][jj][1] + b2, 0.f), rv1);
            rv2 = fmaf(w3, fmaxf(acc[i][jj][2] + b2, 0.f), rv2);
            rv3 = fmaf(w3, fmaxf(acc[i][jj][3] + b2, 0.f), rv3);
        }
        #pragma unroll
        for (int m = 1; m < 16; m <<= 1) {
            rv0 += __shfl_xor(rv0, m, 64);
            rv1 += __shfl_xor(rv1, m, 64);
            rv2 += __shfl_xor(rv2, m, 64);
            rv3 += __shfl_xor(rv3, m, 64);
        }
        if (l15 == 0) {
            int base = (tail * 4 + (wave & 1) * 2 + i) * 16 + quad * 4;
            sV[base + 0] = rv0; sV[base + 1] = rv1;
            sV[base + 2] = rv2; sV[base + 3] = rv3;
        }
    }
    __syncthreads();
    if (tid < 64) {
        float s = 0.5f * (sV[tid] + sV[64 + tid]) + kb3[0];
        float sp = fmaxf(s, 0.f) + log1pf(expf(-fabsf(s)));
        int n_l = tid >> 4, m_l = tid & 15;
        R[(size_t)(b * NPTS + n0 + n_l) * NPTS + m0 + m_l] = sp;
    }
}

// ============ fused multilateration setup + solve + epilogue ============
__global__ __launch_bounds__(256) void k_solve(
    const float* __restrict__ R, const float* __restrict__ anchor_pts,
    const float* __restrict__ action_pts, const float* __restrict__ weight,
    float* __restrict__ out)
{
    const int a0 = blockIdx.x * 32, b = blockIdx.y;
    __shared__ float apx[256], apy[256], apz[256], sq[256];
    __shared__ float red[256];
    __shared__ float mb[12];
    const int t = threadIdx.x;
    const float px = anchor_pts[b * 768 + t];
    const float py = anchor_pts[b * 768 + 256 + t];
    const float pz = anchor_pts[b * 768 + 512 + t];
    apx[t] = px; apy[t] = py; apz[t] = pz;
    sq[t] = px * px + py * py + pz * pz;
    float sums[9];
    {
        float vals[9] = {px, py, pz, px*px, px*py, px*pz, py*py, py*pz, pz*pz};
        #pragma unroll
        for (int k = 0; k < 9; ++k) {
            red[t] = vals[k]; __syncthreads();
            for (int s = 128; s > 0; s >>= 1) {
                if (t < s) red[t] += red[t + s];
                __syncthreads();
            }
            sums[k] = red[0]; __syncthreads();
        }
    }
    if (t == 0) {
        const float inv = 1.f / 256.f;
        float mx = sums[0]*inv, my = sums[1]*inv, mz = sums[2]*inv;
        float a_ = sums[3]*inv - mx*mx;
        float b_ = sums[4]*inv - mx*my;
        float c_ = sums[5]*inv - mx*mz;
        float d_ = sums[6]*inv - my*my;
        float e_ = sums[7]*inv - my*mz;
        float f_ = sums[8]*inv - mz*mz;
        float c00 = d_*f_ - e_*e_;
        float c01 = c_*e_ - b_*f_;
        float c02 = b_*e_ - c_*d_;
        float det = a_*c00 + b_*c01 + c_*c02;
        float id = 1.f / det;
        mb[0] = mx; mb[1] = my; mb[2] = mz;
        mb[3] = c00*id;  mb[4] = c01*id;             mb[5] = c02*id;
        mb[6] = c01*id;  mb[7] = (a_*f_ - c_*c_)*id; mb[8] = (b_*c_ - a_*e_)*id;
        mb[9] = c02*id;  mb[10] = (b_*c_ - a_*e_)*id; mb[11] = (a_*d_ - b_*b_)*id;
    }
    __syncthreads();
    const int ar = a0 + (t >> 3), l8 = t & 7;
    const float Pbx = mb[0], Pby = mb[1], Pbz = mb[2];
    const float* Rrow = R + (size_t)(b * NPTS + ar) * NPTS;
    float v0 = 0.f, v1 = 0.f, v2 = 0.f;
    #pragma unroll 4
    for (int k = 0; k < 32; ++k) {
        int n = l8 + (k << 3);
        float Rv = Rrow[n];
        float cc = sq[n] - Rv * Rv;
        v0 = fmaf(cc, apx[n] - Pbx, v0);
        v1 = fmaf(cc, apy[n] - Pby, v1);
        v2 = fmaf(cc, apz[n] - Pbz, v2);
    }
    #pragma unroll
    for (int m = 1; m < 8; m <<= 1) {
        v0 += __shfl_xor(v0, m, 64);
        v1 += __shfl_xor(v1, m, 64);
        v2 += __shfl_xor(v2, m, 64);
    }
    if (l8 == 0) {
        const float sc = 0.5f / 256.f;
        v0 *= sc; v1 *= sc; v2 *= sc;
        float p0 = mb[3]*v0 + mb[4]*v1 + mb[5]*v2;
        float p1 = mb[6]*v0 + mb[7]*v1 + mb[8]*v2;
        float p2 = mb[9]*v0 + mb[10]*v1 + mb[11]*v2;
        float f0 = p0 - action_pts[b * 768 + ar];
        float f1 = p1 - action_pts[b * 768 + 256 + ar];
        float f2 = p2 - action_pts[b * 768 + 512 + ar];
        float wv = weight[b * NPTS + ar];
        out[b * 1024 + ar]              = f0;
        out[b * 1024 + 256 + ar]        = f1;
        out[b * 1024 + 512 + ar]        = f2;
        out[b * 1024 + 768 + ar]        = wv;
        out[2048 + b * 768 + ar]        = f0;
        out[2048 + b * 768 + 256 + ar]  = f1;
        out[2048 + b * 768 + 512 + ar]  = f2;
        out[3584 + b * 768 + ar]        = p0;
        out[3584 + b * 768 + 256 + ar]  = p1;
        out[3584 + b * 768 + 512 + ar]  = p2;
    }
}

extern "C" void kernel_launch(void* const* d_in, const int* in_sizes, int n_in,
                              void* d_out, int out_size, void* d_ws, size_t ws_size,
                              hipStream_t stream)
{
    const float* embA       = (const float*)d_in[0];
    const float* embB       = (const float*)d_in[1];
    const float* action_pts = (const float*)d_in[2];
    const float* anchor_pts = (const float*)d_in[3];
    const float* kw1 = (const float*)d_in[4];
    const float* kb1 = (const float*)d_in[5];
    const float* kw2 = (const float*)d_in[6];
    const float* kb2 = (const float*)d_in[7];
    const float* kw3 = (const float*)d_in[8];
    const float* kb3 = (const float*)d_in[9];
    const float* pw0 = (const float*)d_in[10];
    const float* pb0 = (const float*)d_in[11];
    const float* pw1 = (const float*)d_in[12];
    const float* pb1 = (const float*)d_in[13];
    const float* pw2 = (const float*)d_in[14];
    const float* pb2 = (const float*)d_in[15];
    const float* pw3 = (const float*)d_in[16];
    const float* pb3 = (const float*)d_in[17];
    const float* pw4 = (const float*)d_in[18];
    const float* pb4 = (const float*)d_in[19];
    const float* headw = (const float*)d_in[20];
    char* wsb = (char*)d_ws;
    float* out = (float*)d_out;

    _Float16* ap    = (_Float16*)(wsb + OFF_AP);
    _Float16* kw2ff = (_Float16*)(wsb + OFF_KW2F);
    _Float16* pnw   = (_Float16*)(wsb + OFF_PNW);
    _Float16* kw1f  = (_Float16*)(wsb + OFF_KW1F);
    float*    R     = (float*)(wsb + OFF_R);
    float*    wgt   = (float*)(wsb + OFF_WGT);

    hipLaunchKernelGGL(k_prep, dim3(1868), dim3(256), 0, stream,
                       kw2, kw1, pw0, pw1, pw2, pw3, pw4, kw2ff, pnw, kw1f);
    hipLaunchKernelGGL(k_mid, dim3(16, 10), dim3(256), 0, stream,
                       embA, embB, kw1f, kb1, ap,
                       pnw, pb0, pb1, pb2, pb3, pb4, headw, wgt);
    hipLaunchKernelGGL(k_pair, dim3(16, 64, 2), dim3(256), 0, stream,
                       ap, kw2ff, kb2, kw3, kb3, R);
    hipLaunchKernelGGL(k_solve, dim3(8, 2), dim3(256), 0, stream,
                       R, anchor_pts, action_pts, wgt, out);
}